// Round 1
// baseline (947.896 us; speedup 1.0000x reference)
//
#include <hip/hip_runtime.h>

#define N_NODES 50000
#define N_FEAT  128
#define N_HID   64
#define N_LAYER 4
#define N_CLASS 40
#define N_EDGES 800000

// ---------------- degree / norm precompute ----------------

__global__ void k_init_deg(float* __restrict__ deg) {
    int i = blockIdx.x * blockDim.x + threadIdx.x;
    if (i < N_NODES) deg[i] = 1.0f;   // +1 self loop
}

__global__ void k_count(const int* __restrict__ dst, float* __restrict__ deg) {
    int e = blockIdx.x * blockDim.x + threadIdx.x;
    if (e < N_EDGES) atomicAdd(&deg[dst[e]], 1.0f);
}

__global__ void k_dinv(const float* __restrict__ deg, float* __restrict__ dinv,
                       float* __restrict__ selfn) {
    int i = blockIdx.x * blockDim.x + threadIdx.x;
    if (i < N_NODES) {
        float d = deg[i];
        dinv[i]  = 1.0f / sqrtf(d);
        selfn[i] = 1.0f / d;
    }
}

__global__ void k_norm_e(const int* __restrict__ src, const int* __restrict__ dst,
                         const float* __restrict__ dinv, float* __restrict__ ne) {
    int e = blockIdx.x * blockDim.x + threadIdx.x;
    if (e < N_EDGES) ne[e] = dinv[src[e]] * dinv[dst[e]];
}

// ---------------- GEMM: h = A @ W ; acc = h*selfn + b ----------------
// block = 256 threads = 4 nodes x 64 output cols. W is [K,64] row-major.

template <int K>
__global__ void k_gemm(const float* __restrict__ A, const float* __restrict__ W,
                       const float* __restrict__ b, const float* __restrict__ selfn,
                       float* __restrict__ h, float* __restrict__ acc) {
    __shared__ float As[4][K];
    int j  = threadIdx.x & 63;
    int nl = threadIdx.x >> 6;
    int node0 = blockIdx.x * 4;

    for (int idx = threadIdx.x; idx < 4 * K; idx += 256) {
        int r = idx / K, c = idx % K;
        int n = node0 + r;
        As[r][c] = (n < N_NODES) ? A[(size_t)n * K + c] : 0.0f;
    }
    __syncthreads();

    int n = node0 + nl;
    if (n >= N_NODES) return;

    float s = 0.0f;
#pragma unroll
    for (int k = 0; k < K; k++)
        s = fmaf(As[nl][k], W[k * 64 + j], s);   // As broadcast; W coalesced

    h[(size_t)n * 64 + j]   = s;                         // raw h for messages
    acc[(size_t)n * 64 + j] = fmaf(s, selfn[n], b[j]);   // self-loop + bias
}

// ---------------- edge scatter: acc[dst] += h[src] * norm_e ----------------
// 64 lanes per edge, one feature per lane.

__global__ void k_scatter(const int* __restrict__ src, const int* __restrict__ dst,
                          const float* __restrict__ ne, const float* __restrict__ h,
                          float* __restrict__ acc) {
    long long t = (long long)blockIdx.x * blockDim.x + threadIdx.x;
    int e = (int)(t >> 6);
    int j = (int)(t & 63);
    if (e >= N_EDGES) return;
    int s = src[e], d = dst[e];
    float v = h[(size_t)s * 64 + j] * ne[e];
    atomicAdd(&acc[(size_t)d * 64 + j], v);
}

// ---------------- relu ----------------

__global__ void k_relu(const float* __restrict__ acc, float* __restrict__ out) {
    int i = blockIdx.x * blockDim.x + threadIdx.x;
    if (i < N_NODES * 64) out[i] = fmaxf(acc[i], 0.0f);
}

// ---------------- attention over layers + output projection ----------------
// One 64-lane wave per node; 4 nodes per 256-thread block.
// hs layout: [L][N][64]. scores[l] = ||h_l||^2 (twin streams are identical).

__global__ void k_attn(const float* __restrict__ hs, const float* __restrict__ Wout,
                       const float* __restrict__ bout, float* __restrict__ out) {
    __shared__ float blend[4][64];
    int j  = threadIdx.x & 63;
    int nl = threadIdx.x >> 6;
    int n  = blockIdx.x * 4 + nl;

    float v[N_LAYER], sc[N_LAYER];
#pragma unroll
    for (int l = 0; l < N_LAYER; l++) {
        float val = (n < N_NODES) ? hs[((size_t)l * N_NODES + n) * 64 + j] : 0.0f;
        v[l]  = val;
        sc[l] = val * val;
    }
    // 64-lane butterfly reduction of the 4 score partials
#pragma unroll
    for (int off = 32; off > 0; off >>= 1) {
#pragma unroll
        for (int l = 0; l < N_LAYER; l++) sc[l] += __shfl_xor(sc[l], off, 64);
    }
    // softmax over layers (TEMPERATURE = 1)
    float m = fmaxf(fmaxf(sc[0], sc[1]), fmaxf(sc[2], sc[3]));
    float e[N_LAYER];
    float sum = 0.0f;
#pragma unroll
    for (int l = 0; l < N_LAYER; l++) { e[l] = __expf(sc[l] - m); sum += e[l]; }
    float inv = 1.0f / sum;
    float bl = 0.0f;
#pragma unroll
    for (int l = 0; l < N_LAYER; l++) bl = fmaf(e[l] * inv, v[l], bl);
    blend[nl][j] = bl;
    __syncthreads();

    if (n < N_NODES && j < N_CLASS) {
        float o = bout[j];
#pragma unroll
        for (int k = 0; k < 64; k++)
            o = fmaf(blend[nl][k], Wout[k * N_CLASS + j], o);
        out[(size_t)n * N_CLASS + j] = o;
    }
}

// ---------------- launch ----------------

extern "C" void kernel_launch(void* const* d_in, const int* in_sizes, int n_in,
                              void* d_out, int out_size, void* d_ws, size_t ws_size,
                              hipStream_t stream) {
    const float* x    = (const float*)d_in[0];
    const float* W0   = (const float*)d_in[1];
    const float* b0   = (const float*)d_in[2];
    const float* Ws   = (const float*)d_in[3];
    const float* bs   = (const float*)d_in[4];
    const float* Wout = (const float*)d_in[5];
    const float* bout = (const float*)d_in[6];
    const int*   ei   = (const int*)d_in[7];
    const int* src = ei;
    const int* dst = ei + N_EDGES;
    float* out = (float*)d_out;

    float* ws    = (float*)d_ws;
    float* deg   = ws;                      // N
    float* dinv  = deg   + N_NODES;         // N
    float* selfn = dinv  + N_NODES;         // N
    float* ne    = selfn + N_NODES;         // E
    float* acc   = ne    + N_EDGES;         // N*64
    float* hs    = acc   + (size_t)N_NODES * 64;  // L*N*64

    k_init_deg<<<(N_NODES + 255) / 256, 256, 0, stream>>>(deg);
    k_count  <<<(N_EDGES + 255) / 256, 256, 0, stream>>>(dst, deg);
    k_dinv   <<<(N_NODES + 255) / 256, 256, 0, stream>>>(deg, dinv, selfn);
    k_norm_e <<<(N_EDGES + 255) / 256, 256, 0, stream>>>(src, dst, dinv, ne);

    const float* in = x;
    for (int l = 0; l < N_LAYER; l++) {
        const float* W = (l == 0) ? W0 : Ws + (size_t)(l - 1) * 64 * 64;
        const float* b = (l == 0) ? b0 : bs + (size_t)(l - 1) * 64;
        float* hl = hs + (size_t)l * N_NODES * 64;   // raw h, later overwritten by relu
        if (l == 0)
            k_gemm<128><<<N_NODES / 4, 256, 0, stream>>>(in, W, b, selfn, hl, acc);
        else
            k_gemm<64><<<N_NODES / 4, 256, 0, stream>>>(in, W, b, selfn, hl, acc);
        k_scatter<<<(int)(((long long)N_EDGES * 64 + 255) / 256), 256, 0, stream>>>(
            src, dst, ne, hl, acc);
        k_relu<<<(N_NODES * 64 + 255) / 256, 256, 0, stream>>>(acc, hl);
        in = hl;
    }

    k_attn<<<N_NODES / 4, 256, 0, stream>>>(hs, Wout, bout, out);
}

// Round 2
// 483.534 us; speedup vs baseline: 1.9604x; 1.9604x over previous
//
#include <hip/hip_runtime.h>

#define N_NODES 50000
#define N_FEAT  128
#define N_HID   64
#define N_LAYER 4
#define N_CLASS 40
#define N_EDGES 800000

// ---------------- CSR build ----------------

__global__ void k_zero(int* __restrict__ cnt) {
    int i = blockIdx.x * blockDim.x + threadIdx.x;
    if (i < N_NODES) cnt[i] = 0;
}

__global__ void k_count(const int* __restrict__ dst, int* __restrict__ cnt) {
    int e = blockIdx.x * blockDim.x + threadIdx.x;
    if (e < N_EDGES) atomicAdd(&cnt[dst[e]], 1);
}

// single 1024-thread block: exclusive scan cnt -> cursor; dinv = rsqrt(cnt+1)
__global__ void k_scan(const int* __restrict__ cnt, int* __restrict__ cursor,
                       float* __restrict__ dinv) {
    __shared__ int part[1024];
    const int CH = (N_NODES + 1023) / 1024;   // 49
    int t = threadIdx.x;
    int base = t * CH;
    int s = 0;
    for (int i = 0; i < CH; i++) {
        int idx = base + i;
        if (idx < N_NODES) s += cnt[idx];
    }
    part[t] = s;
    __syncthreads();
    for (int off = 1; off < 1024; off <<= 1) {
        int v = (t >= off) ? part[t - off] : 0;
        __syncthreads();
        part[t] += v;
        __syncthreads();
    }
    int run = (t > 0) ? part[t - 1] : 0;
    for (int i = 0; i < CH; i++) {
        int idx = base + i;
        if (idx < N_NODES) {
            int c = cnt[idx];
            cursor[idx] = run;
            run += c;
            dinv[idx] = rsqrtf((float)(c + 1));
        }
    }
}

// scatter edges into CSR slots; cursor[n] ends at row_end(n)
__global__ void k_fill(const int* __restrict__ src, const int* __restrict__ dst,
                       int* __restrict__ cursor, int* __restrict__ csr_src) {
    int e = blockIdx.x * blockDim.x + threadIdx.x;
    if (e < N_EDGES) {
        int pos = atomicAdd(&cursor[dst[e]], 1);
        csr_src[pos] = src[e];
    }
}

// ---------------- GEMM: hd = (A @ W) * dinv[n] ----------------
// 256 threads = 16 nodes x (64 cols / 4 nodes-per-thread). 50000 % 16 == 0.

template <int K>
__global__ void k_gemm(const float* __restrict__ A, const float* __restrict__ W,
                       const float* __restrict__ dinv, float* __restrict__ hd) {
    __shared__ float As[16][K];
    int tid = threadIdx.x;
    int j  = tid & 63;
    int nl = tid >> 6;              // 0..3
    int node0 = blockIdx.x * 16;

    // cooperative float4 copy of 16 contiguous rows
    const float4* srcp = (const float4*)(A + (size_t)node0 * K);
    float4* dstp = (float4*)&As[0][0];
    for (int idx = tid; idx < 16 * K / 4; idx += 256) dstp[idx] = srcp[idx];
    __syncthreads();

    float acc[4] = {0.f, 0.f, 0.f, 0.f};
#pragma unroll 4
    for (int k = 0; k < K; k++) {
        float w = W[k * 64 + j];    // coalesced, L1-resident
#pragma unroll
        for (int i = 0; i < 4; i++)
            acc[i] = fmaf(As[nl * 4 + i][k], w, acc[i]);  // wave-uniform broadcast
    }
#pragma unroll
    for (int i = 0; i < 4; i++) {
        int n = node0 + nl * 4 + i;
        hd[(size_t)n * 64 + j] = acc[i] * dinv[n];
    }
}

// ---------------- aggregation (pull, no atomics) ----------------
// out[n] = relu((sum_e hd[src_e] + hd[n]) * dinv[n] + b)

__global__ void k_agg(const float* __restrict__ hd, const float* __restrict__ b,
                      const float* __restrict__ dinv, const int* __restrict__ cnt,
                      const int* __restrict__ cursor, const int* __restrict__ csr_src,
                      float* __restrict__ out) {
    int tid = threadIdx.x;
    int j = tid & 63;
    int n = blockIdx.x * 4 + (tid >> 6);

    float self = hd[(size_t)n * 64 + j];
    int end = cursor[n];            // post-fill: row_start + cnt
    int k   = end - cnt[n];
    float s = 0.f;
    for (; k + 4 <= end; k += 4) {
        int s0 = csr_src[k], s1 = csr_src[k + 1];
        int s2 = csr_src[k + 2], s3 = csr_src[k + 3];
        float v0 = hd[(size_t)s0 * 64 + j];
        float v1 = hd[(size_t)s1 * 64 + j];
        float v2 = hd[(size_t)s2 * 64 + j];
        float v3 = hd[(size_t)s3 * 64 + j];
        s += (v0 + v1) + (v2 + v3);
    }
    for (; k < end; k++) s += hd[(size_t)csr_src[k] * 64 + j];

    float o = fmaf(s + self, dinv[n], b[j]);
    out[(size_t)n * 64 + j] = fmaxf(o, 0.f);
}

// ---------------- attention over layers + output projection ----------------

__global__ void k_attn(const float* __restrict__ hs, const float* __restrict__ Wout,
                       const float* __restrict__ bout, float* __restrict__ out) {
    __shared__ float blend[4][64];
    int j  = threadIdx.x & 63;
    int nl = threadIdx.x >> 6;
    int n  = blockIdx.x * 4 + nl;

    float v[N_LAYER], sc[N_LAYER];
#pragma unroll
    for (int l = 0; l < N_LAYER; l++) {
        float val = hs[((size_t)l * N_NODES + n) * 64 + j];
        v[l]  = val;
        sc[l] = val * val;
    }
#pragma unroll
    for (int off = 32; off > 0; off >>= 1) {
#pragma unroll
        for (int l = 0; l < N_LAYER; l++) sc[l] += __shfl_xor(sc[l], off, 64);
    }
    float m = fmaxf(fmaxf(sc[0], sc[1]), fmaxf(sc[2], sc[3]));
    float e[N_LAYER];
    float sum = 0.f;
#pragma unroll
    for (int l = 0; l < N_LAYER; l++) { e[l] = __expf(sc[l] - m); sum += e[l]; }
    float inv = 1.f / sum;
    float bl = 0.f;
#pragma unroll
    for (int l = 0; l < N_LAYER; l++) bl = fmaf(e[l] * inv, v[l], bl);
    blend[nl][j] = bl;
    __syncthreads();

    if (j < N_CLASS) {
        float o = bout[j];
#pragma unroll
        for (int k = 0; k < 64; k++)
            o = fmaf(blend[nl][k], Wout[k * N_CLASS + j], o);
        out[(size_t)n * N_CLASS + j] = o;
    }
}

// ---------------- launch ----------------

extern "C" void kernel_launch(void* const* d_in, const int* in_sizes, int n_in,
                              void* d_out, int out_size, void* d_ws, size_t ws_size,
                              hipStream_t stream) {
    const float* x    = (const float*)d_in[0];
    const float* W0   = (const float*)d_in[1];
    const float* b0   = (const float*)d_in[2];
    const float* Ws   = (const float*)d_in[3];
    const float* bs   = (const float*)d_in[4];
    const float* Wout = (const float*)d_in[5];
    const float* bout = (const float*)d_in[6];
    const int*   ei   = (const int*)d_in[7];
    const int* src = ei;
    const int* dst = ei + N_EDGES;
    float* out = (float*)d_out;

    int*   cnt     = (int*)d_ws;                 // N
    int*   cursor  = cnt + N_NODES;              // N
    int*   csr_src = cursor + N_NODES;           // E
    float* dinv    = (float*)(csr_src + N_EDGES);// N
    float* hd      = dinv + N_NODES;             // N*64
    float* hs      = hd + (size_t)N_NODES * 64;  // L*N*64

    k_zero <<<(N_NODES + 255) / 256, 256, 0, stream>>>(cnt);
    k_count<<<(N_EDGES + 255) / 256, 256, 0, stream>>>(dst, cnt);
    k_scan <<<1, 1024, 0, stream>>>(cnt, cursor, dinv);
    k_fill <<<(N_EDGES + 255) / 256, 256, 0, stream>>>(src, dst, cursor, csr_src);

    const float* in = x;
    for (int l = 0; l < N_LAYER; l++) {
        const float* W = (l == 0) ? W0 : Ws + (size_t)(l - 1) * 64 * 64;
        const float* b = (l == 0) ? b0 : bs + (size_t)(l - 1) * 64;
        float* hl = hs + (size_t)l * N_NODES * 64;
        if (l == 0)
            k_gemm<128><<<N_NODES / 16, 256, 0, stream>>>(in, W, dinv, hd);
        else
            k_gemm<64> <<<N_NODES / 16, 256, 0, stream>>>(in, W, dinv, hd);
        k_agg<<<N_NODES / 4, 256, 0, stream>>>(hd, b, dinv, cnt, cursor, csr_src, hl);
        in = hl;
    }

    k_attn<<<N_NODES / 4, 256, 0, stream>>>(hs, Wout, bout, out);
}

// Round 3
// 369.877 us; speedup vs baseline: 2.5627x; 1.3073x over previous
//
#include <hip/hip_runtime.h>

#define N_NODES 50000
#define N_FEAT  128
#define N_HID   64
#define N_LAYER 4
#define N_CLASS 40
#define N_EDGES 800000

#define SCAN_BLK 256
#define N_SBLK ((N_NODES + SCAN_BLK - 1) / SCAN_BLK)   // 196

// ---------------- CSR build ----------------

__global__ void k_zero(int* __restrict__ cnt) {
    int i = blockIdx.x * blockDim.x + threadIdx.x;
    if (i < N_NODES) cnt[i] = 0;
}

__global__ void k_count(const int* __restrict__ dst, int* __restrict__ cnt) {
    int e = blockIdx.x * blockDim.x + threadIdx.x;
    if (e < N_EDGES) atomicAdd(&cnt[dst[e]], 1);
}

// pass 1: per-block exclusive scan of cnt -> cursor; block totals -> bsum
__global__ void k_scan1(const int* __restrict__ cnt, int* __restrict__ cursor,
                        int* __restrict__ bsum) {
    __shared__ int tmp[SCAN_BLK];
    int t = threadIdx.x;
    int i = blockIdx.x * SCAN_BLK + t;
    int v = (i < N_NODES) ? cnt[i] : 0;
    tmp[t] = v;
    __syncthreads();
    for (int off = 1; off < SCAN_BLK; off <<= 1) {
        int u = (t >= off) ? tmp[t - off] : 0;
        __syncthreads();
        tmp[t] += u;
        __syncthreads();
    }
    if (i < N_NODES) cursor[i] = tmp[t] - v;           // exclusive
    if (t == SCAN_BLK - 1) bsum[blockIdx.x] = tmp[t];  // block total
}

// pass 2: single block scans the 196 block sums (exclusive, in place)
__global__ void k_scan2(int* __restrict__ bsum) {
    __shared__ int tmp[SCAN_BLK];
    int t = threadIdx.x;
    int v = (t < N_SBLK) ? bsum[t] : 0;
    tmp[t] = v;
    __syncthreads();
    for (int off = 1; off < SCAN_BLK; off <<= 1) {
        int u = (t >= off) ? tmp[t - off] : 0;
        __syncthreads();
        tmp[t] += u;
        __syncthreads();
    }
    if (t < N_SBLK) bsum[t] = tmp[t] - v;
}

// pass 3: add block offsets; compute dinv = rsqrt(deg+1)
__global__ void k_scan3(const int* __restrict__ bsum, const int* __restrict__ cnt,
                        int* __restrict__ cursor, float* __restrict__ dinv) {
    int i = blockIdx.x * SCAN_BLK + threadIdx.x;
    if (i < N_NODES) {
        cursor[i] += bsum[blockIdx.x];
        dinv[i] = rsqrtf((float)(cnt[i] + 1));
    }
}

// scatter edges into CSR slots; cursor[n] ends at row_end(n)
__global__ void k_fill(const int* __restrict__ src, const int* __restrict__ dst,
                       int* __restrict__ cursor, int* __restrict__ csr_src) {
    int e = blockIdx.x * blockDim.x + threadIdx.x;
    if (e < N_EDGES) {
        int pos = atomicAdd(&cursor[dst[e]], 1);
        csr_src[pos] = src[e];
    }
}

// ---------------- GEMM: hd = (A @ W) * dinv[n] ----------------
// 256 threads = 16 nodes x (64 cols / 4 nodes-per-thread). 50000 % 16 == 0.

template <int K>
__global__ void k_gemm(const float* __restrict__ A, const float* __restrict__ W,
                       const float* __restrict__ dinv, float* __restrict__ hd) {
    __shared__ float As[16][K];
    int tid = threadIdx.x;
    int j  = tid & 63;
    int nl = tid >> 6;              // 0..3
    int node0 = blockIdx.x * 16;

    const float4* srcp = (const float4*)(A + (size_t)node0 * K);
    float4* dstp = (float4*)&As[0][0];
    for (int idx = tid; idx < 16 * K / 4; idx += 256) dstp[idx] = srcp[idx];
    __syncthreads();

    float acc[4] = {0.f, 0.f, 0.f, 0.f};
#pragma unroll 4
    for (int k = 0; k < K; k++) {
        float w = W[k * 64 + j];    // coalesced, L1-resident
#pragma unroll
        for (int i = 0; i < 4; i++)
            acc[i] = fmaf(As[nl * 4 + i][k], w, acc[i]);  // wave-uniform broadcast
    }
#pragma unroll
    for (int i = 0; i < 4; i++) {
        int n = node0 + nl * 4 + i;
        hd[(size_t)n * 64 + j] = acc[i] * dinv[n];
    }
}

// ---------------- aggregation (pull, no atomics) ----------------
// out[n] = relu((sum_e hd[src_e] + hd[n]) * dinv[n] + b)

__global__ void k_agg(const float* __restrict__ hd, const float* __restrict__ b,
                      const float* __restrict__ dinv, const int* __restrict__ cnt,
                      const int* __restrict__ cursor, const int* __restrict__ csr_src,
                      float* __restrict__ out) {
    int tid = threadIdx.x;
    int j = tid & 63;
    int n = blockIdx.x * 4 + (tid >> 6);

    float self = hd[(size_t)n * 64 + j];
    int end = cursor[n];            // post-fill: row_start + cnt
    int k   = end - cnt[n];
    float s = 0.f;
    for (; k + 4 <= end; k += 4) {
        int s0 = csr_src[k], s1 = csr_src[k + 1];
        int s2 = csr_src[k + 2], s3 = csr_src[k + 3];
        float v0 = hd[(size_t)s0 * 64 + j];
        float v1 = hd[(size_t)s1 * 64 + j];
        float v2 = hd[(size_t)s2 * 64 + j];
        float v3 = hd[(size_t)s3 * 64 + j];
        s += (v0 + v1) + (v2 + v3);
    }
    for (; k < end; k++) s += hd[(size_t)csr_src[k] * 64 + j];

    float o = fmaf(s + self, dinv[n], b[j]);
    out[(size_t)n * 64 + j] = fmaxf(o, 0.f);
}

// ---------------- attention over layers + output projection ----------------

__global__ void k_attn(const float* __restrict__ hs, const float* __restrict__ Wout,
                       const float* __restrict__ bout, float* __restrict__ out) {
    __shared__ float blend[4][64];
    int j  = threadIdx.x & 63;
    int nl = threadIdx.x >> 6;
    int n  = blockIdx.x * 4 + nl;

    float v[N_LAYER], sc[N_LAYER];
#pragma unroll
    for (int l = 0; l < N_LAYER; l++) {
        float val = hs[((size_t)l * N_NODES + n) * 64 + j];
        v[l]  = val;
        sc[l] = val * val;
    }
#pragma unroll
    for (int off = 32; off > 0; off >>= 1) {
#pragma unroll
        for (int l = 0; l < N_LAYER; l++) sc[l] += __shfl_xor(sc[l], off, 64);
    }
    float m = fmaxf(fmaxf(sc[0], sc[1]), fmaxf(sc[2], sc[3]));
    float e[N_LAYER];
    float sum = 0.f;
#pragma unroll
    for (int l = 0; l < N_LAYER; l++) { e[l] = __expf(sc[l] - m); sum += e[l]; }
    float inv = 1.f / sum;
    float bl = 0.f;
#pragma unroll
    for (int l = 0; l < N_LAYER; l++) bl = fmaf(e[l] * inv, v[l], bl);
    blend[nl][j] = bl;
    __syncthreads();

    if (j < N_CLASS) {
        float o = bout[j];
#pragma unroll
        for (int k = 0; k < 64; k++)
            o = fmaf(blend[nl][k], Wout[k * N_CLASS + j], o);
        out[(size_t)n * N_CLASS + j] = o;
    }
}

// ---------------- launch ----------------

extern "C" void kernel_launch(void* const* d_in, const int* in_sizes, int n_in,
                              void* d_out, int out_size, void* d_ws, size_t ws_size,
                              hipStream_t stream) {
    const float* x    = (const float*)d_in[0];
    const float* W0   = (const float*)d_in[1];
    const float* b0   = (const float*)d_in[2];
    const float* Ws   = (const float*)d_in[3];
    const float* bs   = (const float*)d_in[4];
    const float* Wout = (const float*)d_in[5];
    const float* bout = (const float*)d_in[6];
    const int*   ei   = (const int*)d_in[7];
    const int* src = ei;
    const int* dst = ei + N_EDGES;
    float* out = (float*)d_out;

    int*   cnt     = (int*)d_ws;                 // N
    int*   cursor  = cnt + N_NODES;              // N
    int*   csr_src = cursor + N_NODES;           // E
    int*   bsum    = csr_src + N_EDGES;          // N_SBLK
    float* dinv    = (float*)(bsum + SCAN_BLK);  // N  (padded past N_SBLK)
    float* hd      = dinv + N_NODES;             // N*64
    float* hs      = hd + (size_t)N_NODES * 64;  // L*N*64

    k_zero <<<(N_NODES + 255) / 256, 256, 0, stream>>>(cnt);
    k_count<<<(N_EDGES + 255) / 256, 256, 0, stream>>>(dst, cnt);
    k_scan1<<<N_SBLK, SCAN_BLK, 0, stream>>>(cnt, cursor, bsum);
    k_scan2<<<1, SCAN_BLK, 0, stream>>>(bsum);
    k_scan3<<<N_SBLK, SCAN_BLK, 0, stream>>>(bsum, cnt, cursor, dinv);
    k_fill <<<(N_EDGES + 255) / 256, 256, 0, stream>>>(src, dst, cursor, csr_src);

    const float* in = x;
    for (int l = 0; l < N_LAYER; l++) {
        const float* W = (l == 0) ? W0 : Ws + (size_t)(l - 1) * 64 * 64;
        const float* b = (l == 0) ? b0 : bs + (size_t)(l - 1) * 64;
        float* hl = hs + (size_t)l * N_NODES * 64;
        if (l == 0)
            k_gemm<128><<<N_NODES / 16, 256, 0, stream>>>(in, W, dinv, hd);
        else
            k_gemm<64> <<<N_NODES / 16, 256, 0, stream>>>(in, W, dinv, hd);
        k_agg<<<N_NODES / 4, 256, 0, stream>>>(hd, b, dinv, cnt, cursor, csr_src, hl);
        in = hl;
    }

    k_attn<<<N_NODES / 4, 256, 0, stream>>>(hs, Wout, bout, out);
}

// Round 4
// 345.260 us; speedup vs baseline: 2.7455x; 1.0713x over previous
//
#include <hip/hip_runtime.h>

#define N_NODES 50000
#define N_HID   64
#define N_LAYER 4
#define N_CLASS 40
#define N_EDGES 800000

#define SCAN_BLK 256
#define N_SBLK ((N_NODES + SCAN_BLK - 1) / SCAN_BLK)   // 196

#define BSHIFT 7
#define BSIZE  128                                      // nodes per bucket
#define NBUCK  ((N_NODES + BSIZE - 1) / BSIZE)          // 391
#define BPAD   16                                       // bucket-cursor stride (64B)

// ---------------- CSR build ----------------

__global__ void k_zero(int* __restrict__ cnt) {
    int i = blockIdx.x * blockDim.x + threadIdx.x;
    if (i < N_NODES) cnt[i] = 0;
}

__global__ void k_count(const int* __restrict__ dst, int* __restrict__ cnt) {
    int e = blockIdx.x * blockDim.x + threadIdx.x;
    if (e < N_EDGES) atomicAdd(&cnt[dst[e]], 1);
}

// pass 1: per-block exclusive scan of cnt -> cursor; block totals -> bsum
__global__ void k_scan1(const int* __restrict__ cnt, int* __restrict__ cursor,
                        int* __restrict__ bsum) {
    __shared__ int tmp[SCAN_BLK];
    int t = threadIdx.x;
    int i = blockIdx.x * SCAN_BLK + t;
    int v = (i < N_NODES) ? cnt[i] : 0;
    tmp[t] = v;
    __syncthreads();
    for (int off = 1; off < SCAN_BLK; off <<= 1) {
        int u = (t >= off) ? tmp[t - off] : 0;
        __syncthreads();
        tmp[t] += u;
        __syncthreads();
    }
    if (i < N_NODES) cursor[i] = tmp[t] - v;           // exclusive
    if (t == SCAN_BLK - 1) bsum[blockIdx.x] = tmp[t];  // block total
}

// pass 2: single block scans the 196 block sums (exclusive, in place)
__global__ void k_scan2(int* __restrict__ bsum) {
    __shared__ int tmp[SCAN_BLK];
    int t = threadIdx.x;
    int v = (t < N_SBLK) ? bsum[t] : 0;
    tmp[t] = v;
    __syncthreads();
    for (int off = 1; off < SCAN_BLK; off <<= 1) {
        int u = (t >= off) ? tmp[t - off] : 0;
        __syncthreads();
        tmp[t] += u;
        __syncthreads();
    }
    if (t < N_SBLK) bsum[t] = tmp[t] - v;
}

// pass 3: add block offsets; dinv = rsqrt(deg+1); init bucket cursors
__global__ void k_scan3(const int* __restrict__ bsum, const int* __restrict__ cnt,
                        int* __restrict__ cursor, float* __restrict__ dinv,
                        int* __restrict__ bcur) {
    int i = blockIdx.x * SCAN_BLK + threadIdx.x;
    if (i < N_NODES) {
        int c = cursor[i] + bsum[blockIdx.x];
        cursor[i] = c;
        dinv[i] = rsqrtf((float)(cnt[i] + 1));
        if ((i & (BSIZE - 1)) == 0) bcur[(i >> BSHIFT) * BPAD] = c;
    }
}

// pass A: append packed (dst<<16)|src into dst-bucket staging (line-packed writes)
__global__ void k_bucket(const int* __restrict__ src, const int* __restrict__ dst,
                         int* __restrict__ bcur, unsigned int* __restrict__ stag) {
    int e = blockIdx.x * blockDim.x + threadIdx.x;
    if (e < N_EDGES) {
        int d = dst[e], s = src[e];
        int p = atomicAdd(&bcur[(d >> BSHIFT) * BPAD], 1);
        stag[p] = ((unsigned int)d << 16) | (unsigned int)s;
    }
}

// pass B: one block per bucket; exact CSR positions via LDS cursors.
// All csr16 writes land in the bucket's contiguous window -> L2-packed.
__global__ void k_csr(const unsigned int* __restrict__ stag, const int* __restrict__ cursor,
                      unsigned short* __restrict__ csr16) {
    __shared__ int lcur[BSIZE];
    int b = blockIdx.x;
    int t = threadIdx.x;
    if (t < BSIZE) {
        int node = (b << BSHIFT) + t;
        lcur[t] = (node < N_NODES) ? cursor[node] : 0;
    }
    __syncthreads();
    int bstart = cursor[b << BSHIFT];
    int bend   = (b == NBUCK - 1) ? N_EDGES : cursor[(b + 1) << BSHIFT];
    for (int i = bstart + t; i < bend; i += blockDim.x) {
        unsigned int rec = stag[i];
        int d = rec >> 16, s = rec & 0xffff;
        int p = atomicAdd(&lcur[d & (BSIZE - 1)], 1);
        csr16[p] = (unsigned short)s;
    }
}

// ---------------- GEMM: hd = (A @ W) * dinv[n] ----------------
// 256 threads = 16 nodes x 64 cols, 4 nodes per thread; float4 LDS broadcasts.

template <int K>
__global__ void k_gemm(const float* __restrict__ A, const float* __restrict__ W,
                       const float* __restrict__ dinv, float* __restrict__ hd) {
    __shared__ float As[16][K];
    int tid = threadIdx.x;
    int j  = tid & 63;
    int nl = tid >> 6;              // 0..3
    int node0 = blockIdx.x * 16;

    const float4* srcp = (const float4*)(A + (size_t)node0 * K);
    float4* dstp = (float4*)&As[0][0];
    for (int idx = tid; idx < 16 * K / 4; idx += 256) dstp[idx] = srcp[idx];
    __syncthreads();

    float acc[4] = {0.f, 0.f, 0.f, 0.f};
#pragma unroll
    for (int k = 0; k < K; k += 4) {
        float4 a0 = *(const float4*)&As[nl * 4 + 0][k];   // same addr across wave: broadcast
        float4 a1 = *(const float4*)&As[nl * 4 + 1][k];
        float4 a2 = *(const float4*)&As[nl * 4 + 2][k];
        float4 a3 = *(const float4*)&As[nl * 4 + 3][k];
        float w0 = W[(k + 0) * 64 + j];
        float w1 = W[(k + 1) * 64 + j];
        float w2 = W[(k + 2) * 64 + j];
        float w3 = W[(k + 3) * 64 + j];
        acc[0] = fmaf(a0.w, w3, fmaf(a0.z, w2, fmaf(a0.y, w1, fmaf(a0.x, w0, acc[0]))));
        acc[1] = fmaf(a1.w, w3, fmaf(a1.z, w2, fmaf(a1.y, w1, fmaf(a1.x, w0, acc[1]))));
        acc[2] = fmaf(a2.w, w3, fmaf(a2.z, w2, fmaf(a2.y, w1, fmaf(a2.x, w0, acc[2]))));
        acc[3] = fmaf(a3.w, w3, fmaf(a3.z, w2, fmaf(a3.y, w1, fmaf(a3.x, w0, acc[3]))));
    }
#pragma unroll
    for (int i = 0; i < 4; i++) {
        int n = node0 + nl * 4 + i;
        hd[(size_t)n * 64 + j] = acc[i] * dinv[n];
    }
}

// ---------------- aggregation (pull, no atomics) ----------------
// out[n] = relu((sum_e hd[src_e] + hd[n]) * dinv[n] + b)

__global__ void k_agg(const float* __restrict__ hd, const float* __restrict__ b,
                      const float* __restrict__ dinv, const int* __restrict__ cnt,
                      const int* __restrict__ cursor,
                      const unsigned short* __restrict__ csr16,
                      float* __restrict__ out) {
    int tid = threadIdx.x;
    int j = tid & 63;
    int n = blockIdx.x * 4 + (tid >> 6);

    float self = hd[(size_t)n * 64 + j];
    int k   = cursor[n];
    int end = k + cnt[n];
    float s = 0.f;
    for (; k + 8 <= end; k += 8) {
        int s0 = csr16[k],     s1 = csr16[k + 1], s2 = csr16[k + 2], s3 = csr16[k + 3];
        int s4 = csr16[k + 4], s5 = csr16[k + 5], s6 = csr16[k + 6], s7 = csr16[k + 7];
        float v0 = hd[(size_t)s0 * 64 + j];
        float v1 = hd[(size_t)s1 * 64 + j];
        float v2 = hd[(size_t)s2 * 64 + j];
        float v3 = hd[(size_t)s3 * 64 + j];
        float v4 = hd[(size_t)s4 * 64 + j];
        float v5 = hd[(size_t)s5 * 64 + j];
        float v6 = hd[(size_t)s6 * 64 + j];
        float v7 = hd[(size_t)s7 * 64 + j];
        s += ((v0 + v1) + (v2 + v3)) + ((v4 + v5) + (v6 + v7));
    }
    for (; k < end; k++) s += hd[(size_t)csr16[k] * 64 + j];

    float o = fmaf(s + self, dinv[n], b[j]);
    out[(size_t)n * 64 + j] = fmaxf(o, 0.f);
}

// ---------------- attention over layers + output projection ----------------

__global__ void k_attn(const float* __restrict__ hs, const float* __restrict__ Wout,
                       const float* __restrict__ bout, float* __restrict__ out) {
    __shared__ float blend[4][64];
    int j  = threadIdx.x & 63;
    int nl = threadIdx.x >> 6;
    int n  = blockIdx.x * 4 + nl;

    float v[N_LAYER], sc[N_LAYER];
#pragma unroll
    for (int l = 0; l < N_LAYER; l++) {
        float val = hs[((size_t)l * N_NODES + n) * 64 + j];
        v[l]  = val;
        sc[l] = val * val;
    }
#pragma unroll
    for (int off = 32; off > 0; off >>= 1) {
#pragma unroll
        for (int l = 0; l < N_LAYER; l++) sc[l] += __shfl_xor(sc[l], off, 64);
    }
    float m = fmaxf(fmaxf(sc[0], sc[1]), fmaxf(sc[2], sc[3]));
    float e[N_LAYER];
    float sum = 0.f;
#pragma unroll
    for (int l = 0; l < N_LAYER; l++) { e[l] = __expf(sc[l] - m); sum += e[l]; }
    float inv = 1.f / sum;
    float bl = 0.f;
#pragma unroll
    for (int l = 0; l < N_LAYER; l++) bl = fmaf(e[l] * inv, v[l], bl);
    blend[nl][j] = bl;
    __syncthreads();

    if (j < N_CLASS) {
        float o = bout[j];
#pragma unroll
        for (int k = 0; k < 64; k++)
            o = fmaf(blend[nl][k], Wout[k * N_CLASS + j], o);
        out[(size_t)n * N_CLASS + j] = o;
    }
}

// ---------------- launch ----------------

extern "C" void kernel_launch(void* const* d_in, const int* in_sizes, int n_in,
                              void* d_out, int out_size, void* d_ws, size_t ws_size,
                              hipStream_t stream) {
    const float* x    = (const float*)d_in[0];
    const float* W0   = (const float*)d_in[1];
    const float* b0   = (const float*)d_in[2];
    const float* Ws   = (const float*)d_in[3];
    const float* bs   = (const float*)d_in[4];
    const float* Wout = (const float*)d_in[5];
    const float* bout = (const float*)d_in[6];
    const int*   ei   = (const int*)d_in[7];
    const int* src = ei;
    const int* dst = ei + N_EDGES;
    float* out = (float*)d_out;

    int*            cnt    = (int*)d_ws;                     // N
    int*            cursor = cnt + N_NODES;                  // N
    unsigned short* csr16  = (unsigned short*)(cursor + N_NODES);  // E ushort
    int*            bcur   = (int*)(csr16 + N_EDGES);        // NBUCK*BPAD
    int*            bsum   = bcur + NBUCK * BPAD;            // SCAN_BLK
    float*          dinv   = (float*)(bsum + SCAN_BLK);      // N
    float*          hd     = dinv + N_NODES;                 // N*64
    float*          hs     = hd + (size_t)N_NODES * 64;      // L*N*64
    unsigned int*   stag   = (unsigned int*)hd;              // E, aliased (pre-GEMM only)

    k_zero  <<<(N_NODES + 255) / 256, 256, 0, stream>>>(cnt);
    k_count <<<(N_EDGES + 255) / 256, 256, 0, stream>>>(dst, cnt);
    k_scan1 <<<N_SBLK, SCAN_BLK, 0, stream>>>(cnt, cursor, bsum);
    k_scan2 <<<1, SCAN_BLK, 0, stream>>>(bsum);
    k_scan3 <<<N_SBLK, SCAN_BLK, 0, stream>>>(bsum, cnt, cursor, dinv, bcur);
    k_bucket<<<(N_EDGES + 255) / 256, 256, 0, stream>>>(src, dst, bcur, stag);
    k_csr   <<<NBUCK, 256, 0, stream>>>(stag, cursor, csr16);

    const float* in = x;
    for (int l = 0; l < N_LAYER; l++) {
        const float* W = (l == 0) ? W0 : Ws + (size_t)(l - 1) * 64 * 64;
        const float* b = (l == 0) ? b0 : bs + (size_t)(l - 1) * 64;
        float* hl = hs + (size_t)l * N_NODES * 64;
        if (l == 0)
            k_gemm<128><<<N_NODES / 16, 256, 0, stream>>>(in, W, dinv, hd);
        else
            k_gemm<64> <<<N_NODES / 16, 256, 0, stream>>>(in, W, dinv, hd);
        k_agg<<<N_NODES / 4, 256, 0, stream>>>(hd, b, dinv, cnt, cursor, csr16, hl);
        in = hl;
    }

    k_attn<<<N_NODES / 4, 256, 0, stream>>>(hs, Wout, bout, out);
}

// Round 5
// 332.938 us; speedup vs baseline: 2.8471x; 1.0370x over previous
//
#include <hip/hip_runtime.h>

#define N_NODES 50000
#define N_HID   64
#define N_LAYER 4
#define N_CLASS 40
#define N_EDGES 800000

#define SCAN_BLK 256
#define N_SBLK ((N_NODES + SCAN_BLK - 1) / SCAN_BLK)   // 196

#define BSHIFT 8
#define BSIZE  256                                      // nodes per bucket
#define NBUCK  ((N_NODES + BSIZE - 1) / BSIZE)          // 196
#define BPAD   16                                       // bucket-cursor stride (64B)
#define EPT    16                                       // edges per thread (bucket pass)
#define BKCHUNK (256 * EPT)                             // 4096 edges per block
#define NBBLK  ((N_EDGES + BKCHUNK - 1) / BKCHUNK)      // 196

// ---------------- CSR build ----------------

__global__ void k_zero(int* __restrict__ cnt) {
    int i = blockIdx.x * blockDim.x + threadIdx.x;
    if (i < N_NODES) cnt[i] = 0;
}

__global__ void k_count(const int* __restrict__ dst, int* __restrict__ cnt) {
    int e = blockIdx.x * blockDim.x + threadIdx.x;
    if (e < N_EDGES) atomicAdd(&cnt[dst[e]], 1);
}

// pass 1: per-block exclusive scan of cnt -> cursor; block totals -> bsum
__global__ void k_scan1(const int* __restrict__ cnt, int* __restrict__ cursor,
                        int* __restrict__ bsum) {
    __shared__ int tmp[SCAN_BLK];
    int t = threadIdx.x;
    int i = blockIdx.x * SCAN_BLK + t;
    int v = (i < N_NODES) ? cnt[i] : 0;
    tmp[t] = v;
    __syncthreads();
    for (int off = 1; off < SCAN_BLK; off <<= 1) {
        int u = (t >= off) ? tmp[t - off] : 0;
        __syncthreads();
        tmp[t] += u;
        __syncthreads();
    }
    if (i < N_NODES) cursor[i] = tmp[t] - v;           // exclusive
    if (t == SCAN_BLK - 1) bsum[blockIdx.x] = tmp[t];  // block total
}

// pass 2: single block scans the 196 block sums (exclusive, in place)
__global__ void k_scan2(int* __restrict__ bsum) {
    __shared__ int tmp[SCAN_BLK];
    int t = threadIdx.x;
    int v = (t < N_SBLK) ? bsum[t] : 0;
    tmp[t] = v;
    __syncthreads();
    for (int off = 1; off < SCAN_BLK; off <<= 1) {
        int u = (t >= off) ? tmp[t - off] : 0;
        __syncthreads();
        tmp[t] += u;
        __syncthreads();
    }
    if (t < N_SBLK) bsum[t] = tmp[t] - v;
}

// pass 3: add block offsets; dinv = rsqrt(deg+1); init bucket cursors
__global__ void k_scan3(const int* __restrict__ bsum, const int* __restrict__ cnt,
                        int* __restrict__ cursor, float* __restrict__ dinv,
                        int* __restrict__ bcur) {
    int i = blockIdx.x * SCAN_BLK + threadIdx.x;
    if (i < N_NODES) {
        int c = cursor[i] + bsum[blockIdx.x];
        cursor[i] = c;
        dinv[i] = rsqrtf((float)(cnt[i] + 1));
        if ((i & (BSIZE - 1)) == 0) bcur[(i >> BSHIFT) * BPAD] = c;
    }
}

// pass A: block-binned append of packed (dst<<16)|src into dst-bucket windows.
// LDS histogram rank + one global range-reserve per (block,bucket) => each
// block writes contiguous runs (~21 recs) => no per-store line amplification.
__global__ void k_bucket(const int* __restrict__ src, const int* __restrict__ dst,
                         int* __restrict__ bcur, unsigned int* __restrict__ stag) {
    __shared__ int lhist[NBUCK];
    __shared__ int gbase[NBUCK];
    int t = threadIdx.x;
    for (int i = t; i < NBUCK; i += 256) lhist[i] = 0;
    __syncthreads();

    int base = blockIdx.x * BKCHUNK;
    unsigned int rec[EPT];
    int br[EPT];
#pragma unroll
    for (int i = 0; i < EPT; i++) {
        int e = base + i * 256 + t;      // coalesced
        if (e < N_EDGES) {
            int d = dst[e], s = src[e];
            int b = d >> BSHIFT;
            int r = atomicAdd(&lhist[b], 1);   // in-block rank within bucket
            rec[i] = ((unsigned int)d << 16) | (unsigned int)s;
            br[i]  = (b << 16) | r;            // r < 4096 fits
        } else {
            br[i] = -1;
        }
    }
    __syncthreads();
    for (int i = t; i < NBUCK; i += 256) {
        int c = lhist[i];
        gbase[i] = c ? atomicAdd(&bcur[i * BPAD], c) : 0;
    }
    __syncthreads();
#pragma unroll
    for (int i = 0; i < EPT; i++) {
        if (br[i] >= 0) {
            int b = br[i] >> 16, r = br[i] & 0xffff;
            stag[gbase[b] + r] = rec[i];
        }
    }
}

// pass B: one block per bucket; exact CSR positions via LDS cursors.
__global__ void k_csr(const unsigned int* __restrict__ stag, const int* __restrict__ cursor,
                      unsigned short* __restrict__ csr16) {
    __shared__ int lcur[BSIZE];
    int b = blockIdx.x;
    int t = threadIdx.x;
    int node0 = b << BSHIFT;
    if (t < BSIZE) {
        int node = node0 + t;
        lcur[t] = (node < N_NODES) ? cursor[node] : 0;
    }
    __syncthreads();
    int bstart = cursor[node0];
    int bend   = (b == NBUCK - 1) ? N_EDGES : cursor[(b + 1) << BSHIFT];
    for (int i = bstart + t; i < bend; i += blockDim.x) {
        unsigned int rec = stag[i];
        int d = rec >> 16, s = rec & 0xffff;
        int p = atomicAdd(&lcur[d & (BSIZE - 1)], 1);
        csr16[p] = (unsigned short)s;
    }
}

// ---------------- GEMM: hd = (A @ W) * dinv[n] ----------------

template <int K>
__global__ void k_gemm(const float* __restrict__ A, const float* __restrict__ W,
                       const float* __restrict__ dinv, float* __restrict__ hd) {
    __shared__ float As[16][K];
    int tid = threadIdx.x;
    int j  = tid & 63;
    int nl = tid >> 6;              // 0..3
    int node0 = blockIdx.x * 16;

    const float4* srcp = (const float4*)(A + (size_t)node0 * K);
    float4* dstp = (float4*)&As[0][0];
    for (int idx = tid; idx < 16 * K / 4; idx += 256) dstp[idx] = srcp[idx];
    __syncthreads();

    float acc[4] = {0.f, 0.f, 0.f, 0.f};
#pragma unroll
    for (int k = 0; k < K; k += 4) {
        float4 a0 = *(const float4*)&As[nl * 4 + 0][k];   // wave-uniform broadcast
        float4 a1 = *(const float4*)&As[nl * 4 + 1][k];
        float4 a2 = *(const float4*)&As[nl * 4 + 2][k];
        float4 a3 = *(const float4*)&As[nl * 4 + 3][k];
        float w0 = W[(k + 0) * 64 + j];
        float w1 = W[(k + 1) * 64 + j];
        float w2 = W[(k + 2) * 64 + j];
        float w3 = W[(k + 3) * 64 + j];
        acc[0] = fmaf(a0.w, w3, fmaf(a0.z, w2, fmaf(a0.y, w1, fmaf(a0.x, w0, acc[0]))));
        acc[1] = fmaf(a1.w, w3, fmaf(a1.z, w2, fmaf(a1.y, w1, fmaf(a1.x, w0, acc[1]))));
        acc[2] = fmaf(a2.w, w3, fmaf(a2.z, w2, fmaf(a2.y, w1, fmaf(a2.x, w0, acc[2]))));
        acc[3] = fmaf(a3.w, w3, fmaf(a3.z, w2, fmaf(a3.y, w1, fmaf(a3.x, w0, acc[3]))));
    }
#pragma unroll
    for (int i = 0; i < 4; i++) {
        int n = node0 + nl * 4 + i;
        hd[(size_t)n * 64 + j] = acc[i] * dinv[n];
    }
}

// ---------------- aggregation (pull, no atomics) ----------------

__global__ void k_agg(const float* __restrict__ hd, const float* __restrict__ b,
                      const float* __restrict__ dinv, const int* __restrict__ cnt,
                      const int* __restrict__ cursor,
                      const unsigned short* __restrict__ csr16,
                      float* __restrict__ out) {
    int tid = threadIdx.x;
    int j = tid & 63;
    int n = blockIdx.x * 4 + (tid >> 6);

    float self = hd[(size_t)n * 64 + j];
    int k   = cursor[n];
    int end = k + cnt[n];
    float s = 0.f;
    for (; k + 8 <= end; k += 8) {
        int s0 = csr16[k],     s1 = csr16[k + 1], s2 = csr16[k + 2], s3 = csr16[k + 3];
        int s4 = csr16[k + 4], s5 = csr16[k + 5], s6 = csr16[k + 6], s7 = csr16[k + 7];
        float v0 = hd[(size_t)s0 * 64 + j];
        float v1 = hd[(size_t)s1 * 64 + j];
        float v2 = hd[(size_t)s2 * 64 + j];
        float v3 = hd[(size_t)s3 * 64 + j];
        float v4 = hd[(size_t)s4 * 64 + j];
        float v5 = hd[(size_t)s5 * 64 + j];
        float v6 = hd[(size_t)s6 * 64 + j];
        float v7 = hd[(size_t)s7 * 64 + j];
        s += ((v0 + v1) + (v2 + v3)) + ((v4 + v5) + (v6 + v7));
    }
    for (; k < end; k++) s += hd[(size_t)csr16[k] * 64 + j];

    float o = fmaf(s + self, dinv[n], b[j]);
    out[(size_t)n * 64 + j] = fmaxf(o, 0.f);
}

// ---------------- attention over layers + output projection ----------------

__global__ void k_attn(const float* __restrict__ hs, const float* __restrict__ Wout,
                       const float* __restrict__ bout, float* __restrict__ out) {
    __shared__ float blend[4][64];
    int j  = threadIdx.x & 63;
    int nl = threadIdx.x >> 6;
    int n  = blockIdx.x * 4 + nl;

    float v[N_LAYER], sc[N_LAYER];
#pragma unroll
    for (int l = 0; l < N_LAYER; l++) {
        float val = hs[((size_t)l * N_NODES + n) * 64 + j];
        v[l]  = val;
        sc[l] = val * val;
    }
#pragma unroll
    for (int off = 32; off > 0; off >>= 1) {
#pragma unroll
        for (int l = 0; l < N_LAYER; l++) sc[l] += __shfl_xor(sc[l], off, 64);
    }
    float m = fmaxf(fmaxf(sc[0], sc[1]), fmaxf(sc[2], sc[3]));
    float e[N_LAYER];
    float sum = 0.f;
#pragma unroll
    for (int l = 0; l < N_LAYER; l++) { e[l] = __expf(sc[l] - m); sum += e[l]; }
    float inv = 1.f / sum;
    float bl = 0.f;
#pragma unroll
    for (int l = 0; l < N_LAYER; l++) bl = fmaf(e[l] * inv, v[l], bl);
    blend[nl][j] = bl;
    __syncthreads();

    if (j < N_CLASS) {
        float o = bout[j];
#pragma unroll
        for (int k = 0; k < 64; k++)
            o = fmaf(blend[nl][k], Wout[k * N_CLASS + j], o);
        out[(size_t)n * N_CLASS + j] = o;
    }
}

// ---------------- launch ----------------

extern "C" void kernel_launch(void* const* d_in, const int* in_sizes, int n_in,
                              void* d_out, int out_size, void* d_ws, size_t ws_size,
                              hipStream_t stream) {
    const float* x    = (const float*)d_in[0];
    const float* W0   = (const float*)d_in[1];
    const float* b0   = (const float*)d_in[2];
    const float* Ws   = (const float*)d_in[3];
    const float* bs   = (const float*)d_in[4];
    const float* Wout = (const float*)d_in[5];
    const float* bout = (const float*)d_in[6];
    const int*   ei   = (const int*)d_in[7];
    const int* src = ei;
    const int* dst = ei + N_EDGES;
    float* out = (float*)d_out;

    int*            cnt    = (int*)d_ws;                     // N
    int*            cursor = cnt + N_NODES;                  // N
    unsigned short* csr16  = (unsigned short*)(cursor + N_NODES);  // E ushort
    int*            bcur   = (int*)(csr16 + N_EDGES);        // NBUCK*BPAD
    int*            bsum   = bcur + NBUCK * BPAD;            // SCAN_BLK
    float*          dinv   = (float*)(bsum + SCAN_BLK);      // N
    float*          hd     = dinv + N_NODES;                 // N*64
    float*          hs     = hd + (size_t)N_NODES * 64;      // L*N*64
    unsigned int*   stag   = (unsigned int*)hd;              // E, aliased (pre-GEMM only)

    k_zero  <<<(N_NODES + 255) / 256, 256, 0, stream>>>(cnt);
    k_count <<<(N_EDGES + 255) / 256, 256, 0, stream>>>(dst, cnt);
    k_scan1 <<<N_SBLK, SCAN_BLK, 0, stream>>>(cnt, cursor, bsum);
    k_scan2 <<<1, SCAN_BLK, 0, stream>>>(bsum);
    k_scan3 <<<N_SBLK, SCAN_BLK, 0, stream>>>(bsum, cnt, cursor, dinv, bcur);
    k_bucket<<<NBBLK, 256, 0, stream>>>(src, dst, bcur, stag);
    k_csr   <<<NBUCK, 256, 0, stream>>>(stag, cursor, csr16);

    const float* in = x;
    for (int l = 0; l < N_LAYER; l++) {
        const float* W = (l == 0) ? W0 : Ws + (size_t)(l - 1) * 64 * 64;
        const float* b = (l == 0) ? b0 : bs + (size_t)(l - 1) * 64;
        float* hl = hs + (size_t)l * N_NODES * 64;
        if (l == 0)
            k_gemm<128><<<N_NODES / 16, 256, 0, stream>>>(in, W, dinv, hd);
        else
            k_gemm<64> <<<N_NODES / 16, 256, 0, stream>>>(in, W, dinv, hd);
        k_agg<<<N_NODES / 4, 256, 0, stream>>>(hd, b, dinv, cnt, cursor, csr16, hl);
        in = hl;
    }

    k_attn<<<N_NODES / 4, 256, 0, stream>>>(hs, Wout, bout, out);
}

// Round 6
// 301.815 us; speedup vs baseline: 3.1407x; 1.1031x over previous
//
#include <hip/hip_runtime.h>
#include <hip/hip_fp16.h>

#define N_NODES 50000
#define N_HID   64
#define N_LAYER 4
#define N_CLASS 40
#define N_EDGES 800000

#define SCAN_BLK 256
#define N_SBLK ((N_NODES + SCAN_BLK - 1) / SCAN_BLK)   // 196

#define BSHIFT 8
#define BSIZE  256                                      // nodes per bucket
#define NBUCK  ((N_NODES + BSIZE - 1) / BSIZE)          // 196
#define BPAD   16                                       // bucket-cursor stride (64B)
#define EPT    16                                       // edges per thread (bucket pass)
#define BKCHUNK (256 * EPT)                             // 4096 edges per block
#define NBBLK  ((N_EDGES + BKCHUNK - 1) / BKCHUNK)      // 196

// ---------------- CSR build ----------------

__global__ void k_zero(int* __restrict__ cnt) {
    int i = blockIdx.x * blockDim.x + threadIdx.x;
    if (i < N_NODES) cnt[i] = 0;
}

__global__ void k_count(const int* __restrict__ dst, int* __restrict__ cnt) {
    int e = blockIdx.x * blockDim.x + threadIdx.x;
    if (e < N_EDGES) atomicAdd(&cnt[dst[e]], 1);
}

// pass 1: per-block exclusive scan of cnt -> cursor; block totals -> bsum
__global__ void k_scan1(const int* __restrict__ cnt, int* __restrict__ cursor,
                        int* __restrict__ bsum) {
    __shared__ int tmp[SCAN_BLK];
    int t = threadIdx.x;
    int i = blockIdx.x * SCAN_BLK + t;
    int v = (i < N_NODES) ? cnt[i] : 0;
    tmp[t] = v;
    __syncthreads();
    for (int off = 1; off < SCAN_BLK; off <<= 1) {
        int u = (t >= off) ? tmp[t - off] : 0;
        __syncthreads();
        tmp[t] += u;
        __syncthreads();
    }
    if (i < N_NODES) cursor[i] = tmp[t] - v;           // exclusive
    if (t == SCAN_BLK - 1) bsum[blockIdx.x] = tmp[t];  // block total
}

// pass 2: single block scans the 196 block sums (exclusive, in place)
__global__ void k_scan2(int* __restrict__ bsum) {
    __shared__ int tmp[SCAN_BLK];
    int t = threadIdx.x;
    int v = (t < N_SBLK) ? bsum[t] : 0;
    tmp[t] = v;
    __syncthreads();
    for (int off = 1; off < SCAN_BLK; off <<= 1) {
        int u = (t >= off) ? tmp[t - off] : 0;
        __syncthreads();
        tmp[t] += u;
        __syncthreads();
    }
    if (t < N_SBLK) bsum[t] = tmp[t] - v;
}

// pass 3: add block offsets; dinv = rsqrt(deg+1); init bucket cursors
__global__ void k_scan3(const int* __restrict__ bsum, const int* __restrict__ cnt,
                        int* __restrict__ cursor, float* __restrict__ dinv,
                        int* __restrict__ bcur) {
    int i = blockIdx.x * SCAN_BLK + threadIdx.x;
    if (i < N_NODES) {
        int c = cursor[i] + bsum[blockIdx.x];
        cursor[i] = c;
        dinv[i] = rsqrtf((float)(cnt[i] + 1));
        if ((i & (BSIZE - 1)) == 0) bcur[(i >> BSHIFT) * BPAD] = c;
    }
}

// pass A: block-binned append of packed (dst<<16)|src into dst-bucket windows.
__global__ void k_bucket(const int* __restrict__ src, const int* __restrict__ dst,
                         int* __restrict__ bcur, unsigned int* __restrict__ stag) {
    __shared__ int lhist[NBUCK];
    __shared__ int gbase[NBUCK];
    int t = threadIdx.x;
    for (int i = t; i < NBUCK; i += 256) lhist[i] = 0;
    __syncthreads();

    int base = blockIdx.x * BKCHUNK;
    unsigned int rec[EPT];
    int br[EPT];
#pragma unroll
    for (int i = 0; i < EPT; i++) {
        int e = base + i * 256 + t;      // coalesced
        if (e < N_EDGES) {
            int d = dst[e], s = src[e];
            int b = d >> BSHIFT;
            int r = atomicAdd(&lhist[b], 1);   // in-block rank within bucket
            rec[i] = ((unsigned int)d << 16) | (unsigned int)s;
            br[i]  = (b << 16) | r;            // r < 4096 fits
        } else {
            br[i] = -1;
        }
    }
    __syncthreads();
    for (int i = t; i < NBUCK; i += 256) {
        int c = lhist[i];
        gbase[i] = c ? atomicAdd(&bcur[i * BPAD], c) : 0;
    }
    __syncthreads();
#pragma unroll
    for (int i = 0; i < EPT; i++) {
        if (br[i] >= 0) {
            int b = br[i] >> 16, r = br[i] & 0xffff;
            stag[gbase[b] + r] = rec[i];
        }
    }
}

// pass B: one block per bucket; exact CSR positions via LDS cursors.
__global__ void k_csr(const unsigned int* __restrict__ stag, const int* __restrict__ cursor,
                      unsigned short* __restrict__ csr16) {
    __shared__ int lcur[BSIZE];
    int b = blockIdx.x;
    int t = threadIdx.x;
    int node0 = b << BSHIFT;
    if (t < BSIZE) {
        int node = node0 + t;
        lcur[t] = (node < N_NODES) ? cursor[node] : 0;
    }
    __syncthreads();
    int bstart = cursor[node0];
    int bend   = (b == NBUCK - 1) ? N_EDGES : cursor[(b + 1) << BSHIFT];
    for (int i = bstart + t; i < bend; i += blockDim.x) {
        unsigned int rec = stag[i];
        int d = rec >> 16, s = rec & 0xffff;
        int p = atomicAdd(&lcur[d & (BSIZE - 1)], 1);
        csr16[p] = (unsigned short)s;
    }
}

// ---------------- GEMM: hd16 = half(h*dinv) ; hl = h*selfn + b (fp32) ----------------

template <int K>
__global__ void k_gemm(const float* __restrict__ A, const float* __restrict__ W,
                       const float* __restrict__ b, const float* __restrict__ dinv,
                       __half* __restrict__ hd16, float* __restrict__ hl) {
    __shared__ float As[16][K];
    int tid = threadIdx.x;
    int j  = tid & 63;
    int nl = tid >> 6;              // 0..3
    int node0 = blockIdx.x * 16;

    const float4* srcp = (const float4*)(A + (size_t)node0 * K);
    float4* dstp = (float4*)&As[0][0];
    for (int idx = tid; idx < 16 * K / 4; idx += 256) dstp[idx] = srcp[idx];
    __syncthreads();

    float acc[4] = {0.f, 0.f, 0.f, 0.f};
#pragma unroll
    for (int k = 0; k < K; k += 4) {
        float4 a0 = *(const float4*)&As[nl * 4 + 0][k];   // wave-uniform broadcast
        float4 a1 = *(const float4*)&As[nl * 4 + 1][k];
        float4 a2 = *(const float4*)&As[nl * 4 + 2][k];
        float4 a3 = *(const float4*)&As[nl * 4 + 3][k];
        float w0 = W[(k + 0) * 64 + j];
        float w1 = W[(k + 1) * 64 + j];
        float w2 = W[(k + 2) * 64 + j];
        float w3 = W[(k + 3) * 64 + j];
        acc[0] = fmaf(a0.w, w3, fmaf(a0.z, w2, fmaf(a0.y, w1, fmaf(a0.x, w0, acc[0]))));
        acc[1] = fmaf(a1.w, w3, fmaf(a1.z, w2, fmaf(a1.y, w1, fmaf(a1.x, w0, acc[1]))));
        acc[2] = fmaf(a2.w, w3, fmaf(a2.z, w2, fmaf(a2.y, w1, fmaf(a2.x, w0, acc[2]))));
        acc[3] = fmaf(a3.w, w3, fmaf(a3.z, w2, fmaf(a3.y, w1, fmaf(a3.x, w0, acc[3]))));
    }
    float bj = b[j];
#pragma unroll
    for (int i = 0; i < 4; i++) {
        int n = node0 + nl * 4 + i;
        float dv = dinv[n];
        hd16[(size_t)n * 64 + j] = __float2half(acc[i] * dv);        // fp16 message
        hl[(size_t)n * 64 + j]   = fmaf(acc[i], dv * dv, bj);        // exact self+bias
    }
}

// ---------------- aggregation (pull, no atomics, fp16 messages) ----------------
// hl[n] = relu(hl[n] + dinv[n] * sum_e hd16[src_e])
// wave = 1 node: 32 feature-pair lanes x 2 edge-parity halves.

__global__ void k_agg(const __half2* __restrict__ hd16, const float* __restrict__ dinv,
                      const int* __restrict__ cnt, const int* __restrict__ cursor,
                      const unsigned short* __restrict__ csr16,
                      float* __restrict__ hl) {
    int tid = threadIdx.x;
    int j  = tid & 31;          // feature pair 0..31
    int hw = (tid >> 5) & 1;    // edge-parity half
    int n  = blockIdx.x * 4 + (tid >> 6);

    int k   = cursor[n];
    int end = k + cnt[n];
    float sx = 0.f, sy = 0.f;
    for (; k + 4 <= end; k += 4) {
        int s0 = csr16[k + hw];
        int s1 = csr16[k + 2 + hw];
        float2 v0 = __half22float2(hd16[(size_t)s0 * 32 + j]);
        float2 v1 = __half22float2(hd16[(size_t)s1 * 32 + j]);
        sx += v0.x + v1.x;
        sy += v0.y + v1.y;
    }
    if (k + 2 <= end) {
        int s0 = csr16[k + hw];
        float2 v0 = __half22float2(hd16[(size_t)s0 * 32 + j]);
        sx += v0.x; sy += v0.y;
        k += 2;
    }
    if (hw == 0 && k < end) {
        int s0 = csr16[k];
        float2 v0 = __half22float2(hd16[(size_t)s0 * 32 + j]);
        sx += v0.x; sy += v0.y;
    }
    sx += __shfl_xor(sx, 32);
    sy += __shfl_xor(sy, 32);

    if (hw == 0) {
        float dv = dinv[n];
        float2 a = ((const float2*)hl)[(size_t)n * 32 + j];
        float ox = fmaxf(fmaf(sx, dv, a.x), 0.f);
        float oy = fmaxf(fmaf(sy, dv, a.y), 0.f);
        ((float2*)hl)[(size_t)n * 32 + j] = make_float2(ox, oy);
    }
}

// ---------------- attention over layers + output projection ----------------

__global__ void k_attn(const float* __restrict__ hs, const float* __restrict__ Wout,
                       const float* __restrict__ bout, float* __restrict__ out) {
    __shared__ float blend[4][64];
    int j  = threadIdx.x & 63;
    int nl = threadIdx.x >> 6;
    int n  = blockIdx.x * 4 + nl;

    float v[N_LAYER], sc[N_LAYER];
#pragma unroll
    for (int l = 0; l < N_LAYER; l++) {
        float val = hs[((size_t)l * N_NODES + n) * 64 + j];
        v[l]  = val;
        sc[l] = val * val;
    }
#pragma unroll
    for (int off = 32; off > 0; off >>= 1) {
#pragma unroll
        for (int l = 0; l < N_LAYER; l++) sc[l] += __shfl_xor(sc[l], off, 64);
    }
    float m = fmaxf(fmaxf(sc[0], sc[1]), fmaxf(sc[2], sc[3]));
    float e[N_LAYER];
    float sum = 0.f;
#pragma unroll
    for (int l = 0; l < N_LAYER; l++) { e[l] = __expf(sc[l] - m); sum += e[l]; }
    float inv = 1.f / sum;
    float bl = 0.f;
#pragma unroll
    for (int l = 0; l < N_LAYER; l++) bl = fmaf(e[l] * inv, v[l], bl);
    blend[nl][j] = bl;
    __syncthreads();

    if (j < N_CLASS) {
        float o = bout[j];
#pragma unroll
        for (int k = 0; k < 64; k++)
            o = fmaf(blend[nl][k], Wout[k * N_CLASS + j], o);
        out[(size_t)n * N_CLASS + j] = o;
    }
}

// ---------------- launch ----------------

extern "C" void kernel_launch(void* const* d_in, const int* in_sizes, int n_in,
                              void* d_out, int out_size, void* d_ws, size_t ws_size,
                              hipStream_t stream) {
    const float* x    = (const float*)d_in[0];
    const float* W0   = (const float*)d_in[1];
    const float* b0   = (const float*)d_in[2];
    const float* Ws   = (const float*)d_in[3];
    const float* bs   = (const float*)d_in[4];
    const float* Wout = (const float*)d_in[5];
    const float* bout = (const float*)d_in[6];
    const int*   ei   = (const int*)d_in[7];
    const int* src = ei;
    const int* dst = ei + N_EDGES;
    float* out = (float*)d_out;

    int*            cnt    = (int*)d_ws;                     // N
    int*            cursor = cnt + N_NODES;                  // N
    unsigned short* csr16  = (unsigned short*)(cursor + N_NODES);  // E ushort
    int*            bcur   = (int*)(csr16 + N_EDGES);        // NBUCK*BPAD
    int*            bsum   = bcur + NBUCK * BPAD;            // SCAN_BLK
    float*          dinv   = (float*)(bsum + SCAN_BLK);      // N
    __half*         hd16   = (__half*)(dinv + N_NODES);      // N*64 half (6.4 MB)
    float*          hs     = (float*)(hd16 + (size_t)N_NODES * 64);  // L*N*64
    unsigned int*   stag   = (unsigned int*)hd16;            // E uint, aliased (pre-GEMM only)

    k_zero  <<<(N_NODES + 255) / 256, 256, 0, stream>>>(cnt);
    k_count <<<(N_EDGES + 255) / 256, 256, 0, stream>>>(dst, cnt);
    k_scan1 <<<N_SBLK, SCAN_BLK, 0, stream>>>(cnt, cursor, bsum);
    k_scan2 <<<1, SCAN_BLK, 0, stream>>>(bsum);
    k_scan3 <<<N_SBLK, SCAN_BLK, 0, stream>>>(bsum, cnt, cursor, dinv, bcur);
    k_bucket<<<NBBLK, 256, 0, stream>>>(src, dst, bcur, stag);
    k_csr   <<<NBUCK, 256, 0, stream>>>(stag, cursor, csr16);

    const float* in = x;
    for (int l = 0; l < N_LAYER; l++) {
        const float* W = (l == 0) ? W0 : Ws + (size_t)(l - 1) * 64 * 64;
        const float* b = (l == 0) ? b0 : bs + (size_t)(l - 1) * 64;
        float* hl = hs + (size_t)l * N_NODES * 64;
        if (l == 0)
            k_gemm<128><<<N_NODES / 16, 256, 0, stream>>>(in, W, b, dinv, hd16, hl);
        else
            k_gemm<64> <<<N_NODES / 16, 256, 0, stream>>>(in, W, b, dinv, hd16, hl);
        k_agg<<<N_NODES / 4, 256, 0, stream>>>((const __half2*)hd16, dinv, cnt, cursor,
                                               csr16, hl);
        in = hl;
    }

    k_attn<<<N_NODES / 4, 256, 0, stream>>>(hs, Wout, bout, out);
}

// Round 7
// 275.088 us; speedup vs baseline: 3.4458x; 1.0972x over previous
//
#include <hip/hip_runtime.h>
#include <hip/hip_fp16.h>

#define N_NODES 50000
#define N_HID   64
#define N_LAYER 4
#define N_CLASS 40
#define N_EDGES 800000

#define SCAN_BLK 256
#define N_SBLK ((N_NODES + SCAN_BLK - 1) / SCAN_BLK)   // 196

#define BSHIFT 8
#define BSIZE  256                                      // nodes per bucket
#define NBUCK  ((N_NODES + BSIZE - 1) / BSIZE)          // 196
#define BPAD   16                                       // bucket-cursor stride (64B)
#define EPT    16                                       // edges per thread (bucket pass)
#define BKCHUNK (256 * EPT)                             // 4096 edges per block
#define NBBLK  ((N_EDGES + BKCHUNK - 1) / BKCHUNK)      // 196

// ---------------- CSR build ----------------

__global__ void k_zero(int* __restrict__ cnt) {
    int i = blockIdx.x * blockDim.x + threadIdx.x;
    if (i < N_NODES) cnt[i] = 0;
}

__global__ void k_count(const int* __restrict__ dst, int* __restrict__ cnt) {
    int e = blockIdx.x * blockDim.x + threadIdx.x;
    if (e < N_EDGES) atomicAdd(&cnt[dst[e]], 1);
}

__global__ void k_scan1(const int* __restrict__ cnt, int* __restrict__ cursor,
                        int* __restrict__ bsum) {
    __shared__ int tmp[SCAN_BLK];
    int t = threadIdx.x;
    int i = blockIdx.x * SCAN_BLK + t;
    int v = (i < N_NODES) ? cnt[i] : 0;
    tmp[t] = v;
    __syncthreads();
    for (int off = 1; off < SCAN_BLK; off <<= 1) {
        int u = (t >= off) ? tmp[t - off] : 0;
        __syncthreads();
        tmp[t] += u;
        __syncthreads();
    }
    if (i < N_NODES) cursor[i] = tmp[t] - v;           // exclusive
    if (t == SCAN_BLK - 1) bsum[blockIdx.x] = tmp[t];  // block total
}

__global__ void k_scan2(int* __restrict__ bsum) {
    __shared__ int tmp[SCAN_BLK];
    int t = threadIdx.x;
    int v = (t < N_SBLK) ? bsum[t] : 0;
    tmp[t] = v;
    __syncthreads();
    for (int off = 1; off < SCAN_BLK; off <<= 1) {
        int u = (t >= off) ? tmp[t - off] : 0;
        __syncthreads();
        tmp[t] += u;
        __syncthreads();
    }
    if (t < N_SBLK) bsum[t] = tmp[t] - v;
}

__global__ void k_scan3(const int* __restrict__ bsum, const int* __restrict__ cnt,
                        int* __restrict__ cursor, float* __restrict__ dinv,
                        int* __restrict__ bcur) {
    int i = blockIdx.x * SCAN_BLK + threadIdx.x;
    if (i < N_NODES) {
        int c = cursor[i] + bsum[blockIdx.x];
        cursor[i] = c;
        dinv[i] = rsqrtf((float)(cnt[i] + 1));
        if ((i & (BSIZE - 1)) == 0) bcur[(i >> BSHIFT) * BPAD] = c;
    }
}

// pass A: block-binned append of packed (dst<<16)|src into dst-bucket windows.
__global__ void k_bucket(const int* __restrict__ src, const int* __restrict__ dst,
                         int* __restrict__ bcur, unsigned int* __restrict__ stag) {
    __shared__ int lhist[NBUCK];
    __shared__ int gbase[NBUCK];
    int t = threadIdx.x;
    for (int i = t; i < NBUCK; i += 256) lhist[i] = 0;
    __syncthreads();

    int base = blockIdx.x * BKCHUNK;
    unsigned int rec[EPT];
    int br[EPT];
#pragma unroll
    for (int i = 0; i < EPT; i++) {
        int e = base + i * 256 + t;      // coalesced
        if (e < N_EDGES) {
            int d = dst[e], s = src[e];
            int b = d >> BSHIFT;
            int r = atomicAdd(&lhist[b], 1);   // in-block rank within bucket
            rec[i] = ((unsigned int)d << 16) | (unsigned int)s;
            br[i]  = (b << 16) | r;
        } else {
            br[i] = -1;
        }
    }
    __syncthreads();
    for (int i = t; i < NBUCK; i += 256) {
        int c = lhist[i];
        gbase[i] = c ? atomicAdd(&bcur[i * BPAD], c) : 0;
    }
    __syncthreads();
#pragma unroll
    for (int i = 0; i < EPT; i++) {
        if (br[i] >= 0) {
            int b = br[i] >> 16, r = br[i] & 0xffff;
            stag[gbase[b] + r] = rec[i];
        }
    }
}

// pass B: one block per bucket; exact CSR positions via LDS cursors.
__global__ void k_csr(const unsigned int* __restrict__ stag, const int* __restrict__ cursor,
                      unsigned short* __restrict__ csr16) {
    __shared__ int lcur[BSIZE];
    int b = blockIdx.x;
    int t = threadIdx.x;
    int node0 = b << BSHIFT;
    if (t < BSIZE) {
        int node = node0 + t;
        lcur[t] = (node < N_NODES) ? cursor[node] : 0;
    }
    __syncthreads();
    int bstart = cursor[node0];
    int bend   = (b == NBUCK - 1) ? N_EDGES : cursor[(b + 1) << BSHIFT];
    for (int i = bstart + t; i < bend; i += blockDim.x) {
        unsigned int rec = stag[i];
        int d = rec >> 16, s = rec & 0xffff;
        int p = atomicAdd(&lcur[d & (BSIZE - 1)], 1);
        csr16[p] = (unsigned short)s;
    }
}

// ---------------- layer-0 GEMM: hd = half((x @ W0) * dinv) ----------------

__global__ void k_gemm0(const float* __restrict__ A, const float* __restrict__ W,
                        const float* __restrict__ dinv, __half* __restrict__ hd) {
    const int K = 128;
    __shared__ float As[16][K];
    int tid = threadIdx.x;
    int j  = tid & 63;
    int nl = tid >> 6;
    int node0 = blockIdx.x * 16;

    const float4* srcp = (const float4*)(A + (size_t)node0 * K);
    float4* dstp = (float4*)&As[0][0];
    for (int idx = tid; idx < 16 * K / 4; idx += 256) dstp[idx] = srcp[idx];
    __syncthreads();

    float acc[4] = {0.f, 0.f, 0.f, 0.f};
#pragma unroll
    for (int k = 0; k < K; k += 4) {
        float4 a0 = *(const float4*)&As[nl * 4 + 0][k];
        float4 a1 = *(const float4*)&As[nl * 4 + 1][k];
        float4 a2 = *(const float4*)&As[nl * 4 + 2][k];
        float4 a3 = *(const float4*)&As[nl * 4 + 3][k];
        float w0 = W[(k + 0) * 64 + j];
        float w1 = W[(k + 1) * 64 + j];
        float w2 = W[(k + 2) * 64 + j];
        float w3 = W[(k + 3) * 64 + j];
        acc[0] = fmaf(a0.w, w3, fmaf(a0.z, w2, fmaf(a0.y, w1, fmaf(a0.x, w0, acc[0]))));
        acc[1] = fmaf(a1.w, w3, fmaf(a1.z, w2, fmaf(a1.y, w1, fmaf(a1.x, w0, acc[1]))));
        acc[2] = fmaf(a2.w, w3, fmaf(a2.z, w2, fmaf(a2.y, w1, fmaf(a2.x, w0, acc[2]))));
        acc[3] = fmaf(a3.w, w3, fmaf(a3.z, w2, fmaf(a3.y, w1, fmaf(a3.x, w0, acc[3]))));
    }
#pragma unroll
    for (int i = 0; i < 4; i++) {
        int n = node0 + nl * 4 + i;
        hd[(size_t)n * 64 + j] = __float2half(acc[i] * dinv[n]);
    }
}

// ---------------- agg stage (device fn): 16-node tile -> fp32 hl in LDS ----------------
// hl[n] = relu(dinv[n]*(sum_e hd[src_e] + hd[n]) + b)

__device__ __forceinline__ void agg_tile(const __half2* __restrict__ hd,
                                         const float* __restrict__ b,
                                         const float* __restrict__ dinv,
                                         const int* __restrict__ cnt,
                                         const int* __restrict__ cursor,
                                         const unsigned short* __restrict__ csr16,
                                         __half* __restrict__ hs_out,   // may be null
                                         float (*As)[64], int node0, int tid) {
    int lane = tid & 63;
    int w    = tid >> 6;            // wave 0..3
    int j    = lane & 31;           // feature pair
    int hw   = lane >> 5;           // edge-parity half
    float bx = b[2 * j], by = b[2 * j + 1];

    for (int nd = 0; nd < 4; nd++) {
        int nloc = w * 4 + nd;
        int n = node0 + nloc;
        int k   = cursor[n];
        int end = k + cnt[n];
        float sx = 0.f, sy = 0.f;
        for (; k + 4 <= end; k += 4) {
            int s0 = csr16[k + hw];
            int s1 = csr16[k + 2 + hw];
            float2 v0 = __half22float2(hd[(size_t)s0 * 32 + j]);
            float2 v1 = __half22float2(hd[(size_t)s1 * 32 + j]);
            sx += v0.x + v1.x;
            sy += v0.y + v1.y;
        }
        if (k + 2 <= end) {
            int s0 = csr16[k + hw];
            float2 v0 = __half22float2(hd[(size_t)s0 * 32 + j]);
            sx += v0.x; sy += v0.y;
            k += 2;
        }
        if (hw == 0 && k < end) {
            int s0 = csr16[k];
            float2 v0 = __half22float2(hd[(size_t)s0 * 32 + j]);
            sx += v0.x; sy += v0.y;
        }
        sx += __shfl_xor(sx, 32);
        sy += __shfl_xor(sy, 32);

        if (hw == 0) {
            float dv = dinv[n];
            float2 sv = __half22float2(hd[(size_t)n * 32 + j]);   // self row
            float ox = fmaxf(fmaf(sx + sv.x, dv, bx), 0.f);
            float oy = fmaxf(fmaf(sy + sv.y, dv, by), 0.f);
            ((float2*)&As[nloc][0])[j] = make_float2(ox, oy);
            if (hs_out)
                ((__half2*)hs_out)[(size_t)n * 32 + j] =
                    __halves2half2(__float2half(ox), __float2half(oy));
        }
    }
}

// ---------------- fused: agg(layer l) + gemm(layer l+1) ----------------

__global__ void k_fused(const __half2* __restrict__ hd_in, const float* __restrict__ b,
                        const float* __restrict__ dinv, const int* __restrict__ cnt,
                        const int* __restrict__ cursor,
                        const unsigned short* __restrict__ csr16,
                        const float* __restrict__ W,
                        __half* __restrict__ hs_out, __half* __restrict__ hd_out) {
    __shared__ float As[16][64];
    int tid = threadIdx.x;
    int node0 = blockIdx.x * 16;

    agg_tile(hd_in, b, dinv, cnt, cursor, csr16, hs_out, As, node0, tid);
    __syncthreads();

    int j  = tid & 63;
    int nl = tid >> 6;
    float acc[4] = {0.f, 0.f, 0.f, 0.f};
#pragma unroll
    for (int k = 0; k < 64; k += 4) {
        float4 a0 = *(const float4*)&As[nl * 4 + 0][k];
        float4 a1 = *(const float4*)&As[nl * 4 + 1][k];
        float4 a2 = *(const float4*)&As[nl * 4 + 2][k];
        float4 a3 = *(const float4*)&As[nl * 4 + 3][k];
        float w0 = W[(k + 0) * 64 + j];
        float w1 = W[(k + 1) * 64 + j];
        float w2 = W[(k + 2) * 64 + j];
        float w3 = W[(k + 3) * 64 + j];
        acc[0] = fmaf(a0.w, w3, fmaf(a0.z, w2, fmaf(a0.y, w1, fmaf(a0.x, w0, acc[0]))));
        acc[1] = fmaf(a1.w, w3, fmaf(a1.z, w2, fmaf(a1.y, w1, fmaf(a1.x, w0, acc[1]))));
        acc[2] = fmaf(a2.w, w3, fmaf(a2.z, w2, fmaf(a2.y, w1, fmaf(a2.x, w0, acc[2]))));
        acc[3] = fmaf(a3.w, w3, fmaf(a3.z, w2, fmaf(a3.y, w1, fmaf(a3.x, w0, acc[3]))));
    }
#pragma unroll
    for (int i = 0; i < 4; i++) {
        int n = node0 + nl * 4 + i;
        hd_out[(size_t)n * 64 + j] = __float2half(acc[i] * dinv[n]);
    }
}

// ---------------- last: agg(layer 3) + layer-attention + output projection ----------------

__global__ void k_last(const __half2* __restrict__ hd_in, const float* __restrict__ b,
                       const float* __restrict__ dinv, const int* __restrict__ cnt,
                       const int* __restrict__ cursor,
                       const unsigned short* __restrict__ csr16,
                       const __half* __restrict__ hs16,   // 3 layers [l][n][64]
                       const float* __restrict__ Wout, const float* __restrict__ bout,
                       float* __restrict__ out) {
    __shared__ float As[16][64];
    int tid = threadIdx.x;
    int node0 = blockIdx.x * 16;

    agg_tile(hd_in, b, dinv, cnt, cursor, csr16, nullptr, As, node0, tid);
    __syncthreads();

    int j  = tid & 63;
    int nl = tid >> 6;
    // per wave: 4 nodes; compute blend, overwrite As row with blended vector
    for (int i = 0; i < 4; i++) {
        int nloc = nl * 4 + i;
        int n = node0 + nloc;
        float v[N_LAYER], sc[N_LAYER];
#pragma unroll
        for (int l = 0; l < 3; l++) {
            float val = __half2float(hs16[((size_t)l * N_NODES + n) * 64 + j]);
            v[l]  = val;
            sc[l] = val * val;
        }
        v[3]  = As[nloc][j];
        sc[3] = v[3] * v[3];
#pragma unroll
        for (int off = 32; off > 0; off >>= 1) {
#pragma unroll
            for (int l = 0; l < N_LAYER; l++) sc[l] += __shfl_xor(sc[l], off, 64);
        }
        float m = fmaxf(fmaxf(sc[0], sc[1]), fmaxf(sc[2], sc[3]));
        float e[N_LAYER];
        float sum = 0.f;
#pragma unroll
        for (int l = 0; l < N_LAYER; l++) { e[l] = __expf(sc[l] - m); sum += e[l]; }
        float inv = 1.f / sum;
        float bl = 0.f;
#pragma unroll
        for (int l = 0; l < N_LAYER; l++) bl = fmaf(e[l] * inv, v[l], bl);
        __syncthreads();              // As row reads (v[3]) done across wave before overwrite
        As[nloc][j] = bl;
    }
    __syncthreads();

    if (j < N_CLASS) {
        for (int i = 0; i < 4; i++) {
            int nloc = nl * 4 + i;
            int n = node0 + nloc;
            float o = bout[j];
#pragma unroll
            for (int k = 0; k < 64; k++)
                o = fmaf(As[nloc][k], Wout[k * N_CLASS + j], o);
            out[(size_t)n * N_CLASS + j] = o;
        }
    }
}

// ---------------- launch ----------------

extern "C" void kernel_launch(void* const* d_in, const int* in_sizes, int n_in,
                              void* d_out, int out_size, void* d_ws, size_t ws_size,
                              hipStream_t stream) {
    const float* x    = (const float*)d_in[0];
    const float* W0   = (const float*)d_in[1];
    const float* b0   = (const float*)d_in[2];
    const float* Ws   = (const float*)d_in[3];
    const float* bs   = (const float*)d_in[4];
    const float* Wout = (const float*)d_in[5];
    const float* bout = (const float*)d_in[6];
    const int*   ei   = (const int*)d_in[7];
    const int* src = ei;
    const int* dst = ei + N_EDGES;
    float* out = (float*)d_out;

    int*            cnt    = (int*)d_ws;                     // N
    int*            cursor = cnt + N_NODES;                  // N
    unsigned short* csr16  = (unsigned short*)(cursor + N_NODES);  // E ushort
    int*            bcur   = (int*)(csr16 + N_EDGES);        // NBUCK*BPAD
    int*            bsum   = bcur + NBUCK * BPAD;            // SCAN_BLK
    float*          dinv   = (float*)(bsum + SCAN_BLK);      // N
    __half*         hdA    = (__half*)(dinv + N_NODES);      // N*64 half
    __half*         hdB    = hdA + (size_t)N_NODES * 64;     // N*64 half
    __half*         hs16   = hdB + (size_t)N_NODES * 64;     // 3*N*64 half
    unsigned int*   stag   = (unsigned int*)hs16;            // E uint, aliased (pre-layer only)

    k_zero  <<<(N_NODES + 255) / 256, 256, 0, stream>>>(cnt);
    k_count <<<(N_EDGES + 255) / 256, 256, 0, stream>>>(dst, cnt);
    k_scan1 <<<N_SBLK, SCAN_BLK, 0, stream>>>(cnt, cursor, bsum);
    k_scan2 <<<1, SCAN_BLK, 0, stream>>>(bsum);
    k_scan3 <<<N_SBLK, SCAN_BLK, 0, stream>>>(bsum, cnt, cursor, dinv, bcur);
    k_bucket<<<NBBLK, 256, 0, stream>>>(src, dst, bcur, stag);
    k_csr   <<<NBUCK, 256, 0, stream>>>(stag, cursor, csr16);

    const int NT = N_NODES / 16;   // 3125 tiles

    k_gemm0<<<NT, 256, 0, stream>>>(x, W0, dinv, hdA);

    // F1: agg(l0) -> hs0 ; gemm(W1) -> hdB
    k_fused<<<NT, 256, 0, stream>>>((const __half2*)hdA, b0, dinv, cnt, cursor, csr16,
                                    Ws + 0 * 64 * 64, hs16 + (size_t)0 * N_NODES * 64, hdB);
    // F2: agg(l1) -> hs1 ; gemm(W2) -> hdA
    k_fused<<<NT, 256, 0, stream>>>((const __half2*)hdB, bs + 0 * 64, dinv, cnt, cursor, csr16,
                                    Ws + 1 * 64 * 64, hs16 + (size_t)1 * N_NODES * 64, hdA);
    // F3: agg(l2) -> hs2 ; gemm(W3) -> hdB
    k_fused<<<NT, 256, 0, stream>>>((const __half2*)hdA, bs + 1 * 64, dinv, cnt, cursor, csr16,
                                    Ws + 2 * 64 * 64, hs16 + (size_t)2 * N_NODES * 64, hdB);
    // F4: agg(l3) + attention + projection
    k_last<<<NT, 256, 0, stream>>>((const __half2*)hdB, bs + 2 * 64, dinv, cnt, cursor, csr16,
                                   hs16, Wout, bout, out);
}